// Round 2
// baseline (1079.298 us; speedup 1.0000x reference)
//
#include <hip/hip_runtime.h>
#include <hip/hip_bf16.h>
#include <math.h>

#define NB 64
#define C1n 4096
#define C2n 128
#define DIMH 512
#define HIDN 516
#define INPN 132
#define EPSF 1e-8f

typedef __hip_bfloat16 bf16;

// workspace layout (float offsets)
enum : size_t {
  OFF_SKC = 0,          // 64   (zero-init)
  OFF_SKX = 64,         // 64   (zero-init)
  OFF_RX  = 128,        // 8192 (zero-init)
  ZERO_FLOATS = 8320,   // memset range
  OFF_K   = 8320,       // 8192
  OFF_INVNK = 16512,    // 64
  OFF_BETA  = 16576,    // 64
  OFF_FLAG  = 16640,    // 64 (probe: 1.0 => inputs are f32, 0.0 => bf16)
  OFF_EKC = 16704,      // 262144
  OFF_EKX = 278848,     // 262144
  OFF_WB  = 540992,     // 1048576 (w_bias, [n][c][4])
  OFF_RB  = 1589568,    // 256
  OFF_SR  = 1589824,    // 33024
  OFF_SZ  = 1622848,    // 33024
  OFF_SNI = 1655872,    // 33024
  OFF_SNH = 1688896,    // 33024
  OFF_E   = 1721920,    // 8192
  OFF_V   = 1730112,    // 8192
  OFF_HOB = 1738304,    // 256
  WS_FLOATS = 1738560   // ~6.95 MB
};

__device__ __forceinline__ float ldf(const void* p, size_t i, int f){
  if(f) return ((const float*)p)[i];
  return __bfloat162float(((const bf16*)p)[i]);
}
__device__ __forceinline__ void stf(void* p, size_t i, float v, int f){
  if(f) ((float*)p)[i] = v;
  else  ((bf16*)p)[i] = __float2bfloat16(v);
}
__device__ __forceinline__ float expc(float x){
  return expf(fminf(fmaxf(x, -60.f), 60.f));
}

// ---------------- K0: dtype probe ----------------
// Genuine bf16 N(0,1) data: max|x| ~ 4. f32 data read as bf16: mantissa-half
// garbage gives thousands of |x| > 1e4 (and NaNs). Threshold 1e4 is decisive.
__global__ void k0_probe(const void* cp, float* __restrict__ ws){
  int t = threadIdx.x; // 256
  __shared__ float red[256];
  const bf16* p = (const bf16*)cp;
  float m = 0.f;
  for(int i = t; i < 8192; i += 256){
    float v = __bfloat162float(p[i]);
    if(v != v) v = 1e30f;           // NaN -> huge
    m = fmaxf(m, fabsf(v));
  }
  red[t] = m;
  __syncthreads();
  for(int s = 128; s; s >>= 1){
    if(t < s) red[t] = fmaxf(red[t], red[t + s]);
    __syncthreads();
  }
  if(t == 0) ws[OFF_FLAG] = (red[0] > 1e4f) ? 1.0f : 0.0f;
}

// ---------------- K1: k = origin_h @ Wk^T + bk ; beta ; 1/||k|| ----------------
__global__ void k1_kbeta(const void* hop, const void* Wk, const void* bk,
                         const void* Wb, const void* bb, float* __restrict__ ws){
  int n = blockIdx.x;
  int t = threadIdx.x; // 256
  int f = (ws[OFF_FLAG] != 0.f);
  __shared__ float h[DIMH];
  __shared__ float kk[C2n];
  for(int d = t; d < DIMH; d += 256) h[d] = ldf(hop, (size_t)n*HIDN + d, f);
  __syncthreads();
  if(t < C2n){
    float acc = 0.f;
    for(int d = 0; d < DIMH; ++d) acc += h[d] * ldf(Wk, (size_t)t*DIMH + d, f);
    acc += ldf(bk, t, f);
    kk[t] = acc;
    ws[OFF_K + n*C2n + t] = acc;
  } else if(t == 128){
    float acc = 0.f;
    for(int d = 0; d < DIMH; ++d) acc += h[d] * ldf(Wb, d, f);
    acc += ldf(bb, 0, f);
    float sp = fmaxf(acc, 0.f) + log1pf(expc(-fabsf(acc)));  // softplus
    ws[OFF_BETA + n] = sp + 1.0f;
  }
  __syncthreads();
  if(t == 0){
    float s = 0.f;
    for(int c = 0; c < C2n; ++c) s += kk[c]*kk[c];
    ws[OFF_INVNK + n] = 1.0f / fmaxf(sqrtf(s), EPSF);
  }
}

// ---------------- K2: cos-sims, exp weights, sums, rx accumulation ----------------
__global__ void k2_score(const void* cp, const void* cx, float* __restrict__ ws){
  int n = blockIdx.y;
  int cbase = blockIdx.x * 256;
  int t = threadIdx.x; // 256
  int f = (ws[OFF_FLAG] != 0.f);
  __shared__ float ks[C2n];
  __shared__ float el[256];
  __shared__ float ra[256], rbv[256];
  __shared__ float red[256];
  __shared__ float sc2[2];
  if(t < C2n) ks[t] = ws[OFF_K + n*C2n + t];
  if(t == 0){ sc2[0] = ws[OFF_INVNK + n]; sc2[1] = ws[OFF_BETA + n]; }
  __syncthreads();

  int c = cbase + t;
  size_t base = ((size_t)n*C1n + c)*C2n;
  float dc = 0.f, ncn = 0.f, dx = 0.f, nxn = 0.f;
  for(int d = 0; d < C2n; ++d){
    float a = ldf(cp, base + d, f);
    float b = ldf(cx, base + d, f);
    float k = ks[d];
    dc += a*k; ncn += a*a;
    dx += b*k; nxn += b*b;
  }
  float invnk = sc2[0], beta = sc2[1];
  float skc = dc / fmaxf(sqrtf(ncn), EPSF) * invnk;
  float skx = dx / fmaxf(sqrtf(nxn), EPSF) * invnk;
  float ekc = expc(skc * beta);   // |beta*s| <= ~3.2: unnormalized softmax safe
  float ekx = expc(skx * beta);
  ws[OFF_EKC + n*C1n + c] = ekc;
  ws[OFF_EKX + n*C1n + c] = ekx;
  el[t] = ekx; ra[t] = ekc; rbv[t] = ekx;
  __syncthreads();
  for(int s = 128; s; s >>= 1){
    if(t < s){ ra[t] += ra[t+s]; rbv[t] += rbv[t+s]; }
    __syncthreads();
  }
  if(t == 0){
    atomicAdd(&ws[OFF_SKC + n], ra[0]);
    atomicAdd(&ws[OFF_SKX + n], rbv[0]);
  }

  // phase B: rx[n][d] += sum_c e_kx[c] * c_xf[c][d]  (d-parallel, L1/L2-hot rows)
  int d = t & 127, half = t >> 7;
  size_t rbase = ((size_t)n*C1n + cbase + half*128)*C2n;
  float acc = 0.f;
  for(int i = 0; i < 128; ++i){
    acc += el[half*128 + i] * ldf(cx, rbase + (size_t)i*C2n + d, f);
  }
  red[t] = acc;
  __syncthreads();
  if(t < 128) atomicAdd(&ws[OFF_RX + n*C2n + t], red[t] + red[t + 128]);
}

// ---------------- K3a: w_bias (roll + softmax over 4 shifts), rb ----------------
__global__ void k3a_wbias(float* __restrict__ ws){
  int n = blockIdx.x;
  int t = threadIdx.x; // 256
  __shared__ float wl[C1n]; // 16KB
  __shared__ float r0[256], r1[256], r2[256], r3[256];
  float invSc = 1.0f / fmaxf(ws[OFF_SKC + n], 1e-30f);
  float invSx = 1.0f / fmaxf(ws[OFF_SKX + n], 1e-30f);
  for(int c = t; c < C1n; c += 256) wl[c] = ws[OFF_EKC + n*C1n + c] * invSc;
  __syncthreads();
  float a0=0.f, a1=0.f, a2=0.f, a3=0.f;
  for(int c = t; c < C1n; c += 256){
    int x = c >> 6, y = c & 63;
    // SHIFTS=((0,1),(1,0),(0,-1),(-1,0)): rolled[x,y]=w[(x-sx)&63,(y-sy)&63]
    float w0 = wl[ (x << 6)            | ((y-1) & 63) ];
    float w1 = wl[ (((x-1) & 63) << 6) | y            ];
    float w2 = wl[ (x << 6)            | ((y+1) & 63) ];
    float w3 = wl[ (((x+1) & 63) << 6) | y            ];
    float m = fmaxf(fmaxf(w0,w1), fmaxf(w2,w3));
    float e0 = expc(w0-m), e1 = expc(w1-m), e2 = expc(w2-m), e3 = expc(w3-m);
    float inv = 1.0f/(e0+e1+e2+e3);
    e0 *= inv; e1 *= inv; e2 *= inv; e3 *= inv;
    size_t wb = OFF_WB + ((size_t)n*C1n + c)*4;
    ws[wb] = e0; ws[wb+1] = e1; ws[wb+2] = e2; ws[wb+3] = e3;
    float wx = ws[OFF_EKX + n*C1n + c] * invSx;
    a0 += wx*e0; a1 += wx*e1; a2 += wx*e2; a3 += wx*e3;
  }
  r0[t]=a0; r1[t]=a1; r2[t]=a2; r3[t]=a3;
  __syncthreads();
  for(int s = 128; s; s >>= 1){
    if(t < s){ r0[t]+=r0[t+s]; r1[t]+=r1[t+s]; r2[t]+=r2[t+s]; r3[t]+=r3[t+s]; }
    __syncthreads();
  }
  if(t == 0){
    ws[OFF_RB + n*4 + 0] = r0[0]; ws[OFF_RB + n*4 + 1] = r1[0];
    ws[OFF_RB + n*4 + 2] = r2[0]; ws[OFF_RB + n*4 + 3] = r3[0];
  }
}

// ---------------- K3b: GRU gate GEMVs (4 kinds) ----------------
__global__ void k3b_gates(const void* hop, const void* Wih, const void* Whh,
                          const void* bih, const void* bhh, float* __restrict__ ws){
  int n = blockIdx.x, g = blockIdx.y;
  int t = threadIdx.x; // 576
  int f = (ws[OFF_FLAG] != 0.f);
  __shared__ float x[INPN];
  __shared__ float h[HIDN];
  if(t < INPN){
    float v;
    if(t < C2n) v = ws[OFF_RX + n*C2n + t] / fmaxf(ws[OFF_SKX + n], 1e-30f);
    else        v = ws[OFF_RB + n*4 + (t - C2n)];
    x[t] = v;
  }
  for(int d = t; d < HIDN; d += 576) h[d] = ldf(hop, (size_t)n*HIDN + d, f);
  __syncthreads();
  if(t < HIDN){
    int j = t;
    float acc = 0.f;
    if(g <= 1){
      int row = g*HIDN + j;
      for(int d = 0; d < INPN; ++d) acc += x[d] * ldf(Wih, (size_t)row*INPN + d, f);
      for(int d = 0; d < HIDN; ++d) acc += h[d] * ldf(Whh, (size_t)row*HIDN + d, f);
      acc += ldf(bih, row, f) + ldf(bhh, row, f);
      ws[(g == 0 ? OFF_SR : OFF_SZ) + n*HIDN + j] = acc;
    } else if(g == 2){
      int row = 2*HIDN + j;
      for(int d = 0; d < INPN; ++d) acc += x[d] * ldf(Wih, (size_t)row*INPN + d, f);
      acc += ldf(bih, row, f);
      ws[OFF_SNI + n*HIDN + j] = acc;
    } else {
      int row = 2*HIDN + j;
      for(int d = 0; d < HIDN; ++d) acc += h[d] * ldf(Whh, (size_t)row*HIDN + d, f);
      acc += ldf(bhh, row, f);
      ws[OFF_SNH + n*HIDN + j] = acc;
    }
  }
}

// ---------------- K3c: GRU combine, h_o out, h_o_bias, e, v ----------------
__global__ void k3c_combine(const void* hop, const void* We, const void* be,
                            const void* Wv, const void* bv,
                            float* __restrict__ ws, void* out){
  int n = blockIdx.x;
  int t = threadIdx.x; // 576
  int f = (ws[OFF_FLAG] != 0.f);
  __shared__ float ho[HIDN];
  if(t < HIDN){
    float sr = ws[OFF_SR  + n*HIDN + t];
    float sz = ws[OFF_SZ  + n*HIDN + t];
    float si = ws[OFF_SNI + n*HIDN + t];
    float sh = ws[OFF_SNH + n*HIDN + t];
    float rg = 1.0f/(1.0f + expc(-sr));
    float zg = 1.0f/(1.0f + expc(-sz));
    float ng = tanhf(si + rg*sh);
    float hv = ldf(hop, (size_t)n*HIDN + t, f);
    float o = (1.0f - zg)*ng + zg*hv;
    ho[t] = o;
    stf(out, (size_t)n*HIDN + t, o, f);
  }
  __syncthreads();
  if(t == 0){
    float a = ho[512], b = ho[513], c = ho[514], d2 = ho[515];
    float m = fmaxf(fmaxf(a,b), fmaxf(c,d2));
    float e0 = expc(a-m), e1 = expc(b-m), e2 = expc(c-m), e3 = expc(d2-m);
    float inv = 1.0f/(e0+e1+e2+e3);
    ws[OFF_HOB + n*4 + 0] = e0*inv; ws[OFF_HOB + n*4 + 1] = e1*inv;
    ws[OFF_HOB + n*4 + 2] = e2*inv; ws[OFF_HOB + n*4 + 3] = e3*inv;
  }
  if(t < 256){
    int c2 = t & 127, sel = t >> 7;
    const void* W = sel ? Wv : We;
    float acc = 0.f;
    for(int d = 0; d < DIMH; ++d) acc += ho[d] * ldf(W, (size_t)c2*DIMH + d, f);
    if(sel) ws[OFF_V + n*C2n + c2] = acc + ldf(bv, c2, f);
    else {
      float e = acc + ldf(be, c2, f);
      ws[OFF_E + n*C2n + c2] = 1.0f/(1.0f + expc(-e));
    }
  }
}

// ---------------- K4: c_new = c_prev*(1 - w_kc*e) + w_write*v ----------------
__global__ void k4_cnew(const void* cp, float* __restrict__ ws, void* out){
  int n = blockIdx.y;
  int cbase = blockIdx.x * 128;
  int t = threadIdx.x; // 128: d = t, coalesced across threads
  int f = (ws[OFF_FLAG] != 0.f);
  float invSc = 1.0f / fmaxf(ws[OFF_SKC + n], 1e-30f);
  float ed = ws[OFF_E + n*C2n + t];
  float vd = ws[OFF_V + n*C2n + t];
  float h0 = ws[OFF_HOB + n*4 + 0], h1 = ws[OFF_HOB + n*4 + 1];
  float h2 = ws[OFF_HOB + n*4 + 2], h3 = ws[OFF_HOB + n*4 + 3];
  for(int i = 0; i < 128; ++i){
    int c = cbase + i;
    float wkc = ws[OFF_EKC + (size_t)n*C1n + c] * invSc;
    size_t wb = OFF_WB + ((size_t)n*C1n + c)*4;
    float wwr = ws[wb]*h0 + ws[wb+1]*h1 + ws[wb+2]*h2 + ws[wb+3]*h3;
    size_t idx = ((size_t)n*C1n + c)*C2n + t;
    float a = ldf(cp, idx, f);
    float o = a*(1.0f - wkc*ed) + wwr*vd;
    stf(out, (size_t)(NB*HIDN) + idx, o, f);
  }
}

extern "C" void kernel_launch(void* const* d_in, const int* in_sizes, int n_in,
                              void* d_out, int out_size, void* d_ws, size_t ws_size,
                              hipStream_t stream){
  const void* hop = d_in[0];
  const void* cp  = d_in[1];
  const void* cx  = d_in[2];
  const void* Wk  = d_in[3];
  const void* bk  = d_in[4];
  const void* Wb  = d_in[5];
  const void* bb  = d_in[6];
  const void* We  = d_in[7];
  const void* be  = d_in[8];
  const void* Wv  = d_in[9];
  const void* bv  = d_in[10];
  const void* Wih = d_in[11];
  const void* Whh = d_in[12];
  const void* bih = d_in[13];
  const void* bhh = d_in[14];
  float* ws = (float*)d_ws;

  // zero the atomic accumulators (SKC, SKX, RX)
  hipMemsetAsync(ws, 0, ZERO_FLOATS * sizeof(float), stream);

  k0_probe<<<1, 256, 0, stream>>>(cp, ws);
  k1_kbeta<<<NB, 256, 0, stream>>>(hop, Wk, bk, Wb, bb, ws);
  k2_score<<<dim3(16, NB), 256, 0, stream>>>(cp, cx, ws);
  k3a_wbias<<<NB, 256, 0, stream>>>(ws);
  k3b_gates<<<dim3(NB, 4), 576, 0, stream>>>(hop, Wih, Whh, bih, bhh, ws);
  k3c_combine<<<NB, 576, 0, stream>>>(hop, We, be, Wv, bv, ws, d_out);
  k4_cnew<<<dim3(32, NB), 128, 0, stream>>>(cp, ws, d_out);
}